// Round 5
// baseline (579.387 us; speedup 1.0000x reference)
//
#include <hip/hip_runtime.h>
#include <math.h>

// ---------------------------------------------------------------------------
// HimNet multimode v9. B=8,N=1000,CIN=16,H=64,D=16,K=3,XIN=80,K*XIN=240,2H=128
//
// v9 = v8 + forced A-fragment register residency.
// v8 failed because the compiler sank the afr LDS reads back into the d-loop
// (As stays valid, so ds_read remat is legal; VGPR_Count=92 proved it) ->
// 32 ds_read_b128/tile/wave, LDS-read+latency bound, 79us.
// Fix: empty inline-asm "+v" pin on each of the 32 A-fragments after the
// hoist. The asm is a new def, so remat from LDS is illegal; afr must stay
// in VGPRs (~210 total, fits 2 waves/EU). d-loop = 8 coalesced global loads
// + 32 MFMAs per tile per wave, barrier-free.
// packW fragment-linear (v7). cheb GEMMs unchanged.
// ---------------------------------------------------------------------------

typedef __attribute__((ext_vector_type(8))) short s16x8;
typedef __attribute__((ext_vector_type(4))) float f32x4;
typedef unsigned short u16;
typedef unsigned int u32;
typedef unsigned long long u64;

__device__ __forceinline__ u32 f2bf(float f) {
  union { float f; u32 u; } v; v.f = f;
  return (v.u + 0x7FFFu + ((v.u >> 16) & 1u)) >> 16;  // RNE
}
__device__ __forceinline__ float bf2f(u16 h) {
  union { u32 u; float f; } v; v.u = (u32)h << 16; return v.f;
}
__device__ __forceinline__ void glds16(const u16* g, u16* l) {
  __builtin_amdgcn_global_load_lds(
      (const __attribute__((address_space(1))) void*)g,
      (__attribute__((address_space(3))) void*)l, 16, 0, 0);
}

// ---------------------------------------------------------------------------
// prep: S16[3][1024][1024], Xt[3][640][1024], Ag kc0 slots, AgU x-slots,
// K-pads, n-pad rows of T1t/ZSt/SZ1t.
// ---------------------------------------------------------------------------
#define E0 3145728
#define E1 1966080
#define E2 1920000
#define E3 384000
#define E4 384000
#define E5 384000
#define E6 119808
// total = 8303616 = 32436 * 256

struct PrepArgs {
  const float* x[3]; const float* st[3]; const float* S[3];
  u16 *S16, *Xt, *Ag, *AgU, *T1t, *ZSt, *SZ1t;
};

__global__ void prep(PrepArgs P) {
  long idx = (long)blockIdx.x * 256 + threadIdx.x;
  if (idx < E0) {  // S16 incl pads
    int m = (int)(idx >> 20); int rem = (int)(idx & 1048575);
    int n = rem >> 10, k = rem & 1023;
    float v = (n < 1000 && k < 1000) ? P.S[m][n * 1000 + k] : 0.f;
    P.S16[(size_t)m * 1048576 + rem] = (u16)f2bf(v); return;
  }
  idx -= E0;
  if (idx < E1) {  // Xt incl n-pads
    int m = (int)(idx / 655360); int rem = (int)(idx % 655360);
    int col = rem >> 10, nn = rem & 1023;
    int b = col / 80, c = col % 80;
    float v = 0.f;
    if (nn < 1000) v = (c < 16) ? P.x[m][(b * 1000 + nn) * 16 + c]
                                : P.st[m][(b * 1000 + nn) * 64 + c - 16];
    P.Xt[(size_t)m * 655360 + rem] = (u16)f2bf(v); return;
  }
  idx -= E1;
  if (idx < E2) {  // Ag kc0 (cols 0..79)
    int m = (int)(idx / 640000); int rem = (int)(idx % 640000);
    int r = rem / 80, c = rem % 80;
    int n = r >> 3, b = r & 7;
    float v = (c < 16) ? P.x[m][(b * 1000 + n) * 16 + c]
                       : P.st[m][(b * 1000 + n) * 64 + c - 16];
    P.Ag[(size_t)m * 2048000 + (size_t)r * 256 + c] = (u16)f2bf(v); return;
  }
  idx -= E2;
  if (idx < E3) {  // Ag K-pad 240..255
    int m = (int)(idx / 128000); int rem = (int)(idx % 128000);
    int r = rem / 16, c = 240 + rem % 16;
    P.Ag[(size_t)m * 2048000 + (size_t)r * 256 + c] = 0; return;
  }
  idx -= E3;
  if (idx < E4) {  // AgU kc0 x-part (cols 0..15)
    int m = (int)(idx / 128000); int rem = (int)(idx % 128000);
    int r = rem / 16, c = rem % 16;
    int n = r >> 3, b = r & 7;
    P.AgU[(size_t)m * 2048000 + (size_t)r * 256 + c] =
        (u16)f2bf(P.x[m][(b * 1000 + n) * 16 + c]); return;
  }
  idx -= E4;
  if (idx < E5) {  // AgU K-pad
    int m = (int)(idx / 128000); int rem = (int)(idx % 128000);
    int r = rem / 16, c = 240 + rem % 16;
    P.AgU[(size_t)m * 2048000 + (size_t)r * 256 + c] = 0; return;
  }
  idx -= E5;
  if (idx < E6) {  // n-pad rows (k=1000..1023) of T1t/ZSt/SZ1t
    int m = (int)(idx / 39936); int rem = (int)(idx % 39936);
    if (rem < 15360) { int col = rem / 24, j = rem % 24;
      P.T1t[(size_t)m * 655360 + col * 1024 + 1000 + j] = 0; }
    else if (rem < 27648) { int e = rem - 15360; int col = e / 24, j = e % 24;
      P.ZSt[(size_t)m * 524288 + col * 1024 + 1000 + j] = 0; }
    else { int e = rem - 27648; int col = e / 24, j = e % 24;
      P.SZ1t[(size_t)m * 524288 + col * 1024 + 1000 + j] = 0; }
    return;
  }
}

// ---------------------------------------------------------------------------
// bias: outB[mode][n*O+o] = sum_d emb[n,d]*me[mode,d]*Bp[d,o]
// ---------------------------------------------------------------------------
__global__ void bias_kernel(const float* __restrict__ e0, const float* __restrict__ e1,
                            const float* __restrict__ e2, const float* __restrict__ me,
                            const float* __restrict__ Bp, int O, float* __restrict__ outB) {
  int idx = blockIdx.x * blockDim.x + threadIdx.x;
  int total = 3 * 1000 * O;
  if (idx >= total) return;
  int mode = idx / (1000 * O);
  int rem  = idx % (1000 * O);
  int n = rem / O, o = rem % O;
  const float* emb = (mode == 0) ? e0 : (mode == 1) ? e1 : e2;
  float s = 0.f;
#pragma unroll
  for (int d = 0; d < 16; ++d)
    s += emb[n * 16 + d] * me[mode * 16 + d] * Bp[d * O + o];
  outB[idx] = s;
}

// ---------------------------------------------------------------------------
// packW fragment-linear: Bt_f[((d*J + j)*8 + ki)*64 + lane][e] =
//   W[d][k][o],  k = ki*32 + (lane>>4)*8 + e,  o = j*16 + (lane&15), 0 pad.
// Gate J=8 (O=128), update J=4 (O=64).
// ---------------------------------------------------------------------------
__global__ void packW_kernel(const float* __restrict__ Wg, const float* __restrict__ Wu,
                             u16* __restrict__ BtG, u16* __restrict__ BtU) {
  int idx = blockIdx.x * blockDim.x + threadIdx.x;
  if (idx >= (2048 + 1024) * 256) return;
  if (idx < 524288) {          // gate
    int e = idx & 7, lane = (idx >> 3) & 63, ki = (idx >> 9) & 7;
    int j = (idx >> 12) & 7, d = idx >> 15;
    int k = ki * 32 + (lane >> 4) * 8 + e;
    int o = j * 16 + (lane & 15);
    BtG[idx] = (k < 240) ? (u16)f2bf(Wg[d * 30720 + k * 128 + o]) : (u16)0;
  } else {                     // update
    int i2 = idx - 524288;
    int e = i2 & 7, lane = (i2 >> 3) & 63, ki = (i2 >> 9) & 7;
    int j = (i2 >> 12) & 3, d = i2 >> 14;
    int k = ki * 32 + (lane >> 4) * 8 + e;
    int o = j * 16 + (lane & 15);
    BtU[i2] = (k < 240) ? (u16)f2bf(Wu[d * 15360 + k * 64 + o]) : (u16)0;
  }
}

// ---------------------------------------------------------------------------
// cheb_v4: D[f][n] = alpha*sum_k A[f][k]*S16[n][k] (+beta*Res[f][n])
// Tile 64(f) x 64(n), BK=64, 256 thr = 4 waves in 2x2 grid (32x32 each).
// glds staging, XOR chunk swizzle c^(row&7). flags: 1=hasRes,2=hasY,4=hasAgX
// ---------------------------------------------------------------------------
struct ChebArgs2 {
  const u16* S16[3]; const u16* A[3]; const u16* Res[3];
  u16* Yt[3]; u16* AgA[3]; u16* AgX[3];
};

__global__ __launch_bounds__(256, 2) void cheb_v4(ChebArgs2 g, int fdiv, int agbase,
                                                  float alpha, float beta, int flags) {
  const int mode = blockIdx.z;
  const u16* __restrict__ Ab = g.A[mode];
  const u16* __restrict__ Sb = g.S16[mode];

  __shared__ u16 As[64 * 64];
  __shared__ u16 Bs[64 * 64];

  const int t = threadIdx.x;
  const int row0 = blockIdx.y * 64, n0 = blockIdx.x * 64;
  const int lane = t & 63, wid = t >> 6;
  const int l16 = lane & 15, quad = lane >> 4;
  const int wy = (wid >> 1) * 32, wx = (wid & 1) * 32;

  f32x4 acc[2][2];
#pragma unroll
  for (int a = 0; a < 2; ++a)
#pragma unroll
    for (int b = 0; b < 2; ++b) acc[a][b] = (f32x4){0.f, 0.f, 0.f, 0.f};

  for (int k0 = 0; k0 < 1024; k0 += 64) {
#pragma unroll
    for (int p = 0; p < 2; ++p) {  // A: 64x64 = 512 chunks
      int idx = p * 256 + t; int row = idx >> 3; int cs = (idx & 7) ^ (row & 7);
      glds16(Ab + (size_t)(row0 + row) * 1024 + k0 + cs * 8, &As[idx * 8]);
    }
#pragma unroll
    for (int p = 0; p < 2; ++p) {  // B: 64x64 = 512 chunks
      int idx = p * 256 + t; int row = idx >> 3; int cs = (idx & 7) ^ (row & 7);
      glds16(Sb + (size_t)(n0 + row) * 1024 + k0 + cs * 8, &Bs[idx * 8]);
    }
    __syncthreads();
    s16x8 af[2][2], bf[2][2];
#pragma unroll
    for (int mi = 0; mi < 2; ++mi) {
      int row = wy + mi * 16 + l16;
#pragma unroll
      for (int ks = 0; ks < 2; ++ks) {
        int cl = (ks * 4 + quad) ^ (row & 7);
        af[mi][ks] = *(const s16x8*)&As[row * 64 + cl * 8];
      }
    }
#pragma unroll
    for (int ni = 0; ni < 2; ++ni) {
      int row = wx + ni * 16 + l16;
#pragma unroll
      for (int ks = 0; ks < 2; ++ks) {
        int cl = (ks * 4 + quad) ^ (row & 7);
        bf[ni][ks] = *(const s16x8*)&Bs[row * 64 + cl * 8];
      }
    }
#pragma unroll
    for (int ks = 0; ks < 2; ++ks)
#pragma unroll
      for (int mi = 0; mi < 2; ++mi)
#pragma unroll
        for (int ni = 0; ni < 2; ++ni)
          acc[mi][ni] = __builtin_amdgcn_mfma_f32_16x16x32_bf16(af[mi][ks], bf[ni][ks], acc[mi][ni], 0, 0, 0);
    __syncthreads();
  }

#pragma unroll
  for (int mi = 0; mi < 2; ++mi) {
    int frow0 = row0 + wy + mi * 16 + quad * 4;
    int b = frow0 / fdiv, c0 = frow0 - b * fdiv;
#pragma unroll
    for (int ni = 0; ni < 2; ++ni) {
      int n = n0 + wx + ni * 16 + l16;
      if (n < 1000) {
        u16 pk[4];
#pragma unroll
        for (int r = 0; r < 4; ++r) {
          float v = alpha * acc[mi][ni][r];
          if (flags & 1) v += beta * bf2f(g.Res[mode][(size_t)(frow0 + r) * 1024 + n]);
          u16 h = (u16)f2bf(v);
          pk[r] = h;
          if (flags & 2) g.Yt[mode][(size_t)(frow0 + r) * 1024 + n] = h;
        }
        u64 pv = (u64)pk[0] | ((u64)pk[1] << 16) | ((u64)pk[2] << 32) | ((u64)pk[3] << 48);
        *(u64*)&g.AgA[mode][(size_t)(n * 8 + b) * 256 + agbase + c0] = pv;
        if ((flags & 4) && c0 < 16)
          *(u64*)&g.AgX[mode][(size_t)(n * 8 + b) * 256 + agbase + c0] = pv;
      }
    }
  }
}

// ---------------------------------------------------------------------------
// meta3 v9: out[r,o] = act( sum_d ew[n,d] * (A[r,:] . B_d[:,o]) + bias )
// Block: 64 rows x 64 out-cols (oc = blockIdx.x). Wave = 64 rows x 16 cols
// (jw = oc*4 + wid). A staged through LDS once, hoisted to afr[4][8] and
// PINNED in VGPRs via empty asm "+v" (blocks LDS remat - v8's failure).
// Per d-tile: 8 coalesced 1KB B-fragment loads (unique per block,
// L2-resident) + 32 MFMAs. No barriers in the d-loop.
// ---------------------------------------------------------------------------
struct Meta3Args {
  const u16* Ag;        // [3][8000][256]
  const u16* Bt;        // fragment-linear pack
  const float* emb[3];
  const float* me;
  const float* Bias;    // [3][1000][O]
  const float* state[3];
  u16* ZSt;             // [3][512][1024]
  u16* AgU;             // [3][8000][256]
  float* Rb;            // [3][8000][64]
  float* out;
};

__global__ __launch_bounds__(256, 2) void meta3(Meta3Args A, int is_gate, int O) {
  const int mode = blockIdx.z;
  const int row0 = blockIdx.y * 64;
  const int n0 = row0 >> 3;
  const int oc = blockIdx.x;          // out-col block: gate 0/1, update 0
  const int J = O >> 4;               // 16-col groups per d (8 gate, 4 update)

  __shared__ u16 As[64 * 256];   // 32KB: A-prologue stage only
  __shared__ float ewS[8][17];

  const int t = threadIdx.x;
  if (t < 128) {
    int nl = t >> 4, d = t & 15;
    ewS[nl][d] = A.emb[mode][(n0 + nl) * 16 + d] * A.me[mode * 16 + d];
  }

  const int lane = t & 63, wid = t >> 6;
  const int l16 = lane & 15, quad = lane >> 4;
  const u16* Agm = A.Ag + (size_t)mode * 2048000;

  // prologue: stage A rows [row0,row0+64) x K256, hoist to registers
#pragma unroll
  for (int p = 0; p < 8; ++p) {
    int idx = p * 256 + t; int row = idx >> 5; int cs = (idx & 31) ^ (row & 7);
    glds16(Agm + (size_t)(row0 + row) * 256 + cs * 8, &As[idx * 8]);
  }
  __syncthreads();

  s16x8 afr[4][8];   // 128 VGPRs: all 64 rows of A
#pragma unroll
  for (int mi = 0; mi < 4; ++mi) {
    int row = mi * 16 + l16;
#pragma unroll
    for (int ki = 0; ki < 8; ++ki) {
      int cl = (ki * 4 + quad) ^ (row & 7);
      afr[mi][ki] = *(const s16x8*)&As[row * 256 + cl * 8];
    }
  }
  // pin: asm redefines each fragment -> LDS rematerialization is illegal,
  // values must stay in VGPRs across the d-loop.
#pragma unroll
  for (int mi = 0; mi < 4; ++mi)
#pragma unroll
    for (int ki = 0; ki < 8; ++ki)
      asm volatile("" : "+v"(afr[mi][ki]));

  f32x4 outacc[4];
#pragma unroll
  for (int a = 0; a < 4; ++a) outacc[a] = (f32x4){0.f, 0.f, 0.f, 0.f};

  const s16x8* __restrict__ Bf = (const s16x8*)A.Bt;
  const int jw = oc * 4 + wid;        // this wave's 16-col group (global j)

  for (int tl = 0; tl < 16; ++tl) {           // tl == d
    s16x8 bfr[8];
#pragma unroll
    for (int ki = 0; ki < 8; ++ki)
      bfr[ki] = Bf[(((tl * J + jw) * 8 + ki) << 6) + lane];

    f32x4 acc[4];
#pragma unroll
    for (int a = 0; a < 4; ++a) acc[a] = (f32x4){0.f, 0.f, 0.f, 0.f};

#pragma unroll
    for (int ki = 0; ki < 8; ++ki)
#pragma unroll
      for (int mi = 0; mi < 4; ++mi)
        acc[mi] = __builtin_amdgcn_mfma_f32_16x16x32_bf16(afr[mi][ki], bfr[ki], acc[mi], 0, 0, 0);

    // fold d: outacc += ew[n,d] * acc   (node is constant over r for each mi)
#pragma unroll
    for (int mi = 0; mi < 4; ++mi) {
      int nl = (mi * 16 + quad * 4) >> 3;
      float s = ewS[nl][tl];
#pragma unroll
      for (int r = 0; r < 4; ++r)
        outacc[mi][r] += s * acc[mi][r];
    }
  }

  // epilogue: bias + activation + store, straight from registers
  const int o = jw * 16 + l16;        // global out-col (0..O-1)
#pragma unroll
  for (int mi = 0; mi < 4; ++mi)
#pragma unroll
    for (int r = 0; r < 4; ++r) {
      int row = row0 + mi * 16 + quad * 4 + r;
      int n = row >> 3, b = row & 7;
      float pre = outacc[mi][r] + A.Bias[(size_t)mode * 1000 * O + n * O + o];
      if (is_gate) {
        float sg = 1.f / (1.f + __expf(-pre));
        if (o < 64) {
          float st = A.state[mode][(b * 1000 + n) * 64 + o];
          float zs = sg * st;
          A.ZSt[(size_t)mode * 524288 + (size_t)(b * 64 + o) * 1024 + n] = (u16)f2bf(zs);
          A.AgU[(size_t)mode * 2048000 + (size_t)row * 256 + 16 + o] = (u16)f2bf(zs);
        } else {
          A.Rb[(size_t)mode * 512000 + row * 64 + (o - 64)] = sg;
        }
      } else {
        float hc = tanhf(pre);
        float rr = A.Rb[(size_t)mode * 512000 + row * 64 + o];
        float st = A.state[mode][(b * 1000 + n) * 64 + o];
        A.out[(size_t)mode * 512000 + (b * 1000 + n) * 64 + o] = rr * st + (1.f - rr) * hc;
      }
    }
}

// ---------------------------------------------------------------------------
extern "C" void kernel_launch(void* const* d_in, const int* in_sizes, int n_in,
                              void* d_out, int out_size, void* d_ws, size_t ws_size,
                              hipStream_t stream) {
  const float* x[3]   = {(const float*)d_in[0], (const float*)d_in[1], (const float*)d_in[2]};
  const float* st[3]  = {(const float*)d_in[3], (const float*)d_in[4], (const float*)d_in[5]};
  const float* S[3]   = {(const float*)d_in[6], (const float*)d_in[7], (const float*)d_in[8]};
  const float* emb[3] = {(const float*)d_in[9], (const float*)d_in[10], (const float*)d_in[11]};
  const float* me = (const float*)d_in[12];
  const float* Wg = (const float*)d_in[13];
  const float* Bg = (const float*)d_in[14];
  const float* Wu = (const float*)d_in[15];
  const float* Bu = (const float*)d_in[16];
  float* out = (float*)d_out;

  float* BiG = (float*)d_ws;            // 3*1000*128
  float* BiU = BiG + 384000;            // 3*1000*64
  float* Rb  = BiU + 192000;            // 3*8000*64
  u16* S16 = (u16*)(Rb + 1536000);      // 3*1024*1024
  u16* Xt  = S16 + 3145728;             // 3*640*1024
  u16* T1t = Xt + 1966080;              // 3*640*1024
  u16* ZSt = T1t + 1966080;             // 3*512*1024
  u16* SZ1t= ZSt + 1572864;             // 3*512*1024
  u16* Ag  = SZ1t + 1572864;            // 3*8000*256
  u16* AgU = Ag + 6144000;              // 3*8000*256
  u16* BtG = AgU + 6144000;             // 2048*256
  u16* BtU = BtG + 524288;              // 1024*256

  {
    PrepArgs P;
    for (int m = 0; m < 3; ++m) { P.x[m] = x[m]; P.st[m] = st[m]; P.S[m] = S[m]; }
    P.S16 = S16; P.Xt = Xt; P.Ag = Ag; P.AgU = AgU; P.T1t = T1t; P.ZSt = ZSt; P.SZ1t = SZ1t;
    prep<<<32436, 256, 0, stream>>>(P);
  }
  bias_kernel<<<1500, 256, 0, stream>>>(emb[0], emb[1], emb[2], me, Bg, 128, BiG);
  bias_kernel<<<750, 256, 0, stream>>>(emb[0], emb[1], emb[2], me, Bu, 64, BiU);
  packW_kernel<<<3072, 256, 0, stream>>>(Wg, Wu, BtG, BtU);

  // cheb1: T1t = Xt @ S^T -> T1t + Ag[80..159] (+AgU x-part)
  {
    ChebArgs2 a;
    for (int m = 0; m < 3; ++m) {
      a.S16[m] = S16 + (size_t)m * 1048576; a.A[m] = Xt + (size_t)m * 655360;
      a.Res[m] = nullptr; a.Yt[m] = T1t + (size_t)m * 655360;
      a.AgA[m] = Ag + (size_t)m * 2048000; a.AgX[m] = AgU + (size_t)m * 2048000;
    }
    cheb_v4<<<dim3(16, 10, 3), 256, 0, stream>>>(a, 80, 80, 1.f, 0.f, 2 | 4);
  }
  // cheb2: T2t = 2*T1t @ S^T - Xt -> Ag[160..239] (+AgU x-part)
  {
    ChebArgs2 a;
    for (int m = 0; m < 3; ++m) {
      a.S16[m] = S16 + (size_t)m * 1048576; a.A[m] = T1t + (size_t)m * 655360;
      a.Res[m] = Xt + (size_t)m * 655360; a.Yt[m] = nullptr;
      a.AgA[m] = Ag + (size_t)m * 2048000; a.AgX[m] = AgU + (size_t)m * 2048000;
    }
    cheb_v4<<<dim3(16, 10, 3), 256, 0, stream>>>(a, 80, 160, 2.f, -1.f, 1 | 4);
  }
  // gate meta: reads Ag; writes ZSt + AgU[16..79] + Rb  (oc split: grid.x=2)
  {
    Meta3Args a;
    a.Ag = Ag; a.Bt = BtG; a.me = me; a.Bias = BiG;
    a.ZSt = ZSt; a.AgU = AgU; a.Rb = Rb; a.out = out;
    for (int m = 0; m < 3; ++m) { a.emb[m] = emb[m]; a.state[m] = st[m]; }
    meta3<<<dim3(2, 125, 3), 256, 0, stream>>>(a, 1, 128);
  }
  // cheb3: SZ1t = ZSt @ S^T -> SZ1t + AgU[96..159]
  {
    ChebArgs2 a;
    for (int m = 0; m < 3; ++m) {
      a.S16[m] = S16 + (size_t)m * 1048576; a.A[m] = ZSt + (size_t)m * 524288;
      a.Res[m] = nullptr; a.Yt[m] = SZ1t + (size_t)m * 524288;
      a.AgA[m] = AgU + (size_t)m * 2048000; a.AgX[m] = nullptr;
    }
    cheb_v4<<<dim3(16, 8, 3), 256, 0, stream>>>(a, 64, 96, 1.f, 0.f, 2);
  }
  // cheb4: SZ2t = 2*SZ1t @ S^T - ZSt -> AgU[176..239]
  {
    ChebArgs2 a;
    for (int m = 0; m < 3; ++m) {
      a.S16[m] = S16 + (size_t)m * 1048576; a.A[m] = SZ1t + (size_t)m * 524288;
      a.Res[m] = ZSt + (size_t)m * 524288; a.Yt[m] = nullptr;
      a.AgA[m] = AgU + (size_t)m * 2048000; a.AgX[m] = nullptr;
    }
    cheb_v4<<<dim3(16, 8, 3), 256, 0, stream>>>(a, 64, 176, 2.f, -1.f, 1);
  }
  // update meta: reads AgU; writes out
  {
    Meta3Args a;
    a.Ag = AgU; a.Bt = BtU; a.me = me; a.Bias = BiU;
    a.ZSt = ZSt; a.AgU = AgU; a.Rb = Rb; a.out = out;
    for (int m = 0; m < 3; ++m) { a.emb[m] = emb[m]; a.state[m] = st[m]; }
    meta3<<<dim3(1, 125, 3), 256, 0, stream>>>(a, 0, 64);
  }
}

// Round 6
// 409.468 us; speedup vs baseline: 1.4150x; 1.4150x over previous
//
#include <hip/hip_runtime.h>
#include <math.h>

// ---------------------------------------------------------------------------
// HimNet multimode v10. B=8,N=1000,CIN=16,H=64,D=16,K=3,XIN=80,K*XIN=240,2H=128
//
// v10 = v6 + half-tile double-buffered B pipeline in meta3 (T3/T4 at
// 4 blocks/CU).
//   - v9 lesson: afr lives in AGPRs (unified file); never force "v" class.
//   - After A-hoist, the 32KB LDS becomes 2 x 16KB half-tile buffers
//     (K-split of each d-tile). 32 half-steps, counted s_waitcnt vmcnt(4)
//     keeps the next half's 4 glds in flight across barriers; vmcnt(0)
//     only on the last step.
//   - packW back to v6 d-major. cheb GEMMs unchanged.
// ---------------------------------------------------------------------------

typedef __attribute__((ext_vector_type(8))) short s16x8;
typedef __attribute__((ext_vector_type(4))) float f32x4;
typedef unsigned short u16;
typedef unsigned int u32;
typedef unsigned long long u64;

__device__ __forceinline__ u32 f2bf(float f) {
  union { float f; u32 u; } v; v.f = f;
  return (v.u + 0x7FFFu + ((v.u >> 16) & 1u)) >> 16;  // RNE
}
__device__ __forceinline__ float bf2f(u16 h) {
  union { u32 u; float f; } v; v.u = (u32)h << 16; return v.f;
}
__device__ __forceinline__ void glds16(const u16* g, u16* l) {
  __builtin_amdgcn_global_load_lds(
      (const __attribute__((address_space(1))) void*)g,
      (__attribute__((address_space(3))) void*)l, 16, 0, 0);
}

// ---------------------------------------------------------------------------
// prep: S16[3][1024][1024], Xt[3][640][1024], Ag kc0 slots, AgU x-slots,
// K-pads, n-pad rows of T1t/ZSt/SZ1t.
// ---------------------------------------------------------------------------
#define E0 3145728
#define E1 1966080
#define E2 1920000
#define E3 384000
#define E4 384000
#define E5 384000
#define E6 119808
// total = 8303616 = 32436 * 256

struct PrepArgs {
  const float* x[3]; const float* st[3]; const float* S[3];
  u16 *S16, *Xt, *Ag, *AgU, *T1t, *ZSt, *SZ1t;
};

__global__ void prep(PrepArgs P) {
  long idx = (long)blockIdx.x * 256 + threadIdx.x;
  if (idx < E0) {  // S16 incl pads
    int m = (int)(idx >> 20); int rem = (int)(idx & 1048575);
    int n = rem >> 10, k = rem & 1023;
    float v = (n < 1000 && k < 1000) ? P.S[m][n * 1000 + k] : 0.f;
    P.S16[(size_t)m * 1048576 + rem] = (u16)f2bf(v); return;
  }
  idx -= E0;
  if (idx < E1) {  // Xt incl n-pads
    int m = (int)(idx / 655360); int rem = (int)(idx % 655360);
    int col = rem >> 10, nn = rem & 1023;
    int b = col / 80, c = col % 80;
    float v = 0.f;
    if (nn < 1000) v = (c < 16) ? P.x[m][(b * 1000 + nn) * 16 + c]
                                : P.st[m][(b * 1000 + nn) * 64 + c - 16];
    P.Xt[(size_t)m * 655360 + rem] = (u16)f2bf(v); return;
  }
  idx -= E1;
  if (idx < E2) {  // Ag kc0 (cols 0..79)
    int m = (int)(idx / 640000); int rem = (int)(idx % 640000);
    int r = rem / 80, c = rem % 80;
    int n = r >> 3, b = r & 7;
    float v = (c < 16) ? P.x[m][(b * 1000 + n) * 16 + c]
                       : P.st[m][(b * 1000 + n) * 64 + c - 16];
    P.Ag[(size_t)m * 2048000 + (size_t)r * 256 + c] = (u16)f2bf(v); return;
  }
  idx -= E2;
  if (idx < E3) {  // Ag K-pad 240..255
    int m = (int)(idx / 128000); int rem = (int)(idx % 128000);
    int r = rem / 16, c = 240 + rem % 16;
    P.Ag[(size_t)m * 2048000 + (size_t)r * 256 + c] = 0; return;
  }
  idx -= E3;
  if (idx < E4) {  // AgU kc0 x-part (cols 0..15)
    int m = (int)(idx / 128000); int rem = (int)(idx % 128000);
    int r = rem / 16, c = rem % 16;
    int n = r >> 3, b = r & 7;
    P.AgU[(size_t)m * 2048000 + (size_t)r * 256 + c] =
        (u16)f2bf(P.x[m][(b * 1000 + n) * 16 + c]); return;
  }
  idx -= E4;
  if (idx < E5) {  // AgU K-pad
    int m = (int)(idx / 128000); int rem = (int)(idx % 128000);
    int r = rem / 16, c = 240 + rem % 16;
    P.AgU[(size_t)m * 2048000 + (size_t)r * 256 + c] = 0; return;
  }
  idx -= E5;
  if (idx < E6) {  // n-pad rows (k=1000..1023) of T1t/ZSt/SZ1t
    int m = (int)(idx / 39936); int rem = (int)(idx % 39936);
    if (rem < 15360) { int col = rem / 24, j = rem % 24;
      P.T1t[(size_t)m * 655360 + col * 1024 + 1000 + j] = 0; }
    else if (rem < 27648) { int e = rem - 15360; int col = e / 24, j = e % 24;
      P.ZSt[(size_t)m * 524288 + col * 1024 + 1000 + j] = 0; }
    else { int e = rem - 27648; int col = e / 24, j = e % 24;
      P.SZ1t[(size_t)m * 524288 + col * 1024 + 1000 + j] = 0; }
    return;
  }
}

// ---------------------------------------------------------------------------
// bias: outB[mode][n*O+o] = sum_d emb[n,d]*me[mode,d]*Bp[d,o]
// ---------------------------------------------------------------------------
__global__ void bias_kernel(const float* __restrict__ e0, const float* __restrict__ e1,
                            const float* __restrict__ e2, const float* __restrict__ me,
                            const float* __restrict__ Bp, int O, float* __restrict__ outB) {
  int idx = blockIdx.x * blockDim.x + threadIdx.x;
  int total = 3 * 1000 * O;
  if (idx >= total) return;
  int mode = idx / (1000 * O);
  int rem  = idx % (1000 * O);
  int n = rem / O, o = rem % O;
  const float* emb = (mode == 0) ? e0 : (mode == 1) ? e1 : e2;
  float s = 0.f;
#pragma unroll
  for (int d = 0; d < 16; ++d)
    s += emb[n * 16 + d] * me[mode * 16 + d] * Bp[d * O + o];
  outB[idx] = s;
}

// ---------------------------------------------------------------------------
// packW (d-major): Bt[(d*O+o)][k] = bf16(W[d,k,o]) k<240, else 0.
// ---------------------------------------------------------------------------
__global__ void packW_kernel(const float* __restrict__ Wg, const float* __restrict__ Wu,
                             u16* __restrict__ BtG, u16* __restrict__ BtU) {
  int idx = blockIdx.x * blockDim.x + threadIdx.x;
  if (idx >= (2048 + 1024) * 256) return;
  if (idx < 2048 * 256) {
    int col = idx >> 8, k = idx & 255;
    int d = col >> 7, o = col & 127;
    BtG[idx] = (k < 240) ? (u16)f2bf(Wg[d * 30720 + k * 128 + o]) : (u16)0;
  } else {
    int i2 = idx - 2048 * 256;
    int col = i2 >> 8, k = i2 & 255;
    int d = col >> 6, o = col & 63;
    BtU[i2] = (k < 240) ? (u16)f2bf(Wu[d * 15360 + k * 64 + o]) : (u16)0;
  }
}

// ---------------------------------------------------------------------------
// cheb_v4: D[f][n] = alpha*sum_k A[f][k]*S16[n][k] (+beta*Res[f][n])
// Tile 64(f) x 64(n), BK=64, 256 thr = 4 waves in 2x2 grid (32x32 each).
// glds staging, XOR chunk swizzle c^(row&7). flags: 1=hasRes,2=hasY,4=hasAgX
// ---------------------------------------------------------------------------
struct ChebArgs2 {
  const u16* S16[3]; const u16* A[3]; const u16* Res[3];
  u16* Yt[3]; u16* AgA[3]; u16* AgX[3];
};

__global__ __launch_bounds__(256, 2) void cheb_v4(ChebArgs2 g, int fdiv, int agbase,
                                                  float alpha, float beta, int flags) {
  const int mode = blockIdx.z;
  const u16* __restrict__ Ab = g.A[mode];
  const u16* __restrict__ Sb = g.S16[mode];

  __shared__ u16 As[64 * 64];
  __shared__ u16 Bs[64 * 64];

  const int t = threadIdx.x;
  const int row0 = blockIdx.y * 64, n0 = blockIdx.x * 64;
  const int lane = t & 63, wid = t >> 6;
  const int l16 = lane & 15, quad = lane >> 4;
  const int wy = (wid >> 1) * 32, wx = (wid & 1) * 32;

  f32x4 acc[2][2];
#pragma unroll
  for (int a = 0; a < 2; ++a)
#pragma unroll
    for (int b = 0; b < 2; ++b) acc[a][b] = (f32x4){0.f, 0.f, 0.f, 0.f};

  for (int k0 = 0; k0 < 1024; k0 += 64) {
#pragma unroll
    for (int p = 0; p < 2; ++p) {  // A: 64x64 = 512 chunks
      int idx = p * 256 + t; int row = idx >> 3; int cs = (idx & 7) ^ (row & 7);
      glds16(Ab + (size_t)(row0 + row) * 1024 + k0 + cs * 8, &As[idx * 8]);
    }
#pragma unroll
    for (int p = 0; p < 2; ++p) {  // B: 64x64 = 512 chunks
      int idx = p * 256 + t; int row = idx >> 3; int cs = (idx & 7) ^ (row & 7);
      glds16(Sb + (size_t)(n0 + row) * 1024 + k0 + cs * 8, &Bs[idx * 8]);
    }
    __syncthreads();
    s16x8 af[2][2], bf[2][2];
#pragma unroll
    for (int mi = 0; mi < 2; ++mi) {
      int row = wy + mi * 16 + l16;
#pragma unroll
      for (int ks = 0; ks < 2; ++ks) {
        int cl = (ks * 4 + quad) ^ (row & 7);
        af[mi][ks] = *(const s16x8*)&As[row * 64 + cl * 8];
      }
    }
#pragma unroll
    for (int ni = 0; ni < 2; ++ni) {
      int row = wx + ni * 16 + l16;
#pragma unroll
      for (int ks = 0; ks < 2; ++ks) {
        int cl = (ks * 4 + quad) ^ (row & 7);
        bf[ni][ks] = *(const s16x8*)&Bs[row * 64 + cl * 8];
      }
    }
#pragma unroll
    for (int ks = 0; ks < 2; ++ks)
#pragma unroll
      for (int mi = 0; mi < 2; ++mi)
#pragma unroll
        for (int ni = 0; ni < 2; ++ni)
          acc[mi][ni] = __builtin_amdgcn_mfma_f32_16x16x32_bf16(af[mi][ks], bf[ni][ks], acc[mi][ni], 0, 0, 0);
    __syncthreads();
  }

#pragma unroll
  for (int mi = 0; mi < 2; ++mi) {
    int frow0 = row0 + wy + mi * 16 + quad * 4;
    int b = frow0 / fdiv, c0 = frow0 - b * fdiv;
#pragma unroll
    for (int ni = 0; ni < 2; ++ni) {
      int n = n0 + wx + ni * 16 + l16;
      if (n < 1000) {
        u16 pk[4];
#pragma unroll
        for (int r = 0; r < 4; ++r) {
          float v = alpha * acc[mi][ni][r];
          if (flags & 1) v += beta * bf2f(g.Res[mode][(size_t)(frow0 + r) * 1024 + n]);
          u16 h = (u16)f2bf(v);
          pk[r] = h;
          if (flags & 2) g.Yt[mode][(size_t)(frow0 + r) * 1024 + n] = h;
        }
        u64 pv = (u64)pk[0] | ((u64)pk[1] << 16) | ((u64)pk[2] << 32) | ((u64)pk[3] << 48);
        *(u64*)&g.AgA[mode][(size_t)(n * 8 + b) * 256 + agbase + c0] = pv;
        if ((flags & 4) && c0 < 16)
          *(u64*)&g.AgX[mode][(size_t)(n * 8 + b) * 256 + agbase + c0] = pv;
      }
    }
  }
}

// ---------------------------------------------------------------------------
// meta3 v10: out[r,o] = act( sum_d ew[n,d] * (A[r,:] . Btd[d*O+o,:]) + bias )
// Block: 64 rows x 64 out-cols (oc = blockIdx.x). Prologue stages A through
// the 32KB LDS, hoists afr[2][8] (AGPR-resident, no class constraints).
// Then 32 half-steps (16 d x 2 K-halves), B half-tiles (16KB) double-
// buffered in the same 32KB: counted vmcnt(4) + raw barriers, stage of
// half hs+2 issued after the read-retire barrier of half hs.
// 4 waves 2x2 (32 rows x 32 cols). LDS 33.3KB -> 4 blocks/CU.
// ---------------------------------------------------------------------------
struct Meta3Args {
  const u16* Ag;        // [3][8000][256]
  const u16* Bt;        // [O*16][256] d-major
  const float* emb[3];
  const float* me;
  const float* Bias;    // [3][1000][O]
  const float* state[3];
  u16* ZSt;             // [3][512][1024]
  u16* AgU;             // [3][8000][256]
  float* Rb;            // [3][8000][64]
  float* out;
};

__global__ __launch_bounds__(256, 4) void meta3(Meta3Args A, int is_gate, int O) {
  const int mode = blockIdx.z;
  const int row0 = blockIdx.y * 64;
  const int n0 = row0 >> 3;
  const int oc = blockIdx.x;          // out-col block: gate 0/1, update 0
  const int ocbase = oc * 64;

  __shared__ u16 Bs[2][64 * 128];     // 2 x 16KB; prologue uses flat 32KB
  __shared__ float ewS[8][17];

  const int t = threadIdx.x;
  if (t < 128) {
    int nl = t >> 4, d = t & 15;
    ewS[nl][d] = A.emb[mode][(n0 + nl) * 16 + d] * A.me[mode * 16 + d];
  }

  const int lane = t & 63, wid = t >> 6;
  const int l16 = lane & 15, quad = lane >> 4;
  const int wy = (wid >> 1) * 32, wx = (wid & 1) * 32;
  const u16* Agm = A.Ag + (size_t)mode * 2048000;
  u16* Asf = &Bs[0][0];               // flat 32KB view for A prologue

  // prologue: stage A rows [row0,row0+64) x K256, hoist to registers
#pragma unroll
  for (int p = 0; p < 8; ++p) {
    int idx = p * 256 + t; int row = idx >> 5; int cs = (idx & 31) ^ (row & 7);
    glds16(Agm + (size_t)(row0 + row) * 256 + cs * 8, &Asf[idx * 8]);
  }
  asm volatile("s_waitcnt vmcnt(0)" ::: "memory");
  __builtin_amdgcn_s_barrier();

  s16x8 afr[2][8];   // AGPR-resident (unified file); do NOT pin to "v"
#pragma unroll
  for (int mi = 0; mi < 2; ++mi) {
    int row = wy + mi * 16 + l16;
#pragma unroll
    for (int ki = 0; ki < 8; ++ki) {
      int cl = (ki * 4 + quad) ^ (row & 7);
      afr[mi][ki] = *(const s16x8*)&Asf[row * 256 + cl * 8];
    }
  }
  asm volatile("s_waitcnt lgkmcnt(0)" ::: "memory");
  __builtin_amdgcn_s_barrier();

  // half-tile stage: hs -> d = hs>>1, K-half = (hs&1)*128, buf = Bs[hs&1]
#define STAGE_H(HS)                                                         \
  {                                                                         \
    int d_ = (HS) >> 1, k0_ = ((HS) & 1) << 7;                              \
    const u16* src_ = A.Bt + (size_t)(d_ * O + ocbase) * 256 + k0_;         \
    u16* dst_ = &Bs[(HS) & 1][0];                                           \
    _Pragma("unroll")                                                       \
    for (int p_ = 0; p_ < 4; ++p_) {                                        \
      int idx_ = p_ * 256 + t; int row_ = idx_ >> 4;                        \
      int cs_ = (idx_ & 15) ^ (row_ & 7);                                   \
      glds16(src_ + (size_t)row_ * 256 + cs_ * 8, dst_ + idx_ * 8);         \
    }                                                                       \
  }

  STAGE_H(0);
  STAGE_H(1);

  f32x4 outacc[2][2], acc[2][2];
#pragma unroll
  for (int a = 0; a < 2; ++a)
#pragma unroll
    for (int b = 0; b < 2; ++b) {
      outacc[a][b] = (f32x4){0.f, 0.f, 0.f, 0.f};
      acc[a][b] = (f32x4){0.f, 0.f, 0.f, 0.f};
    }

  for (int hs = 0; hs < 32; ++hs) {
    // half hs complete (next half may stay in flight)
    if (hs < 31) asm volatile("s_waitcnt vmcnt(4)" ::: "memory");
    else         asm volatile("s_waitcnt vmcnt(0)" ::: "memory");
    __builtin_amdgcn_s_barrier();

    const u16* buf = &Bs[hs & 1][0];
    const int kbase = (hs & 1) << 2;
#pragma unroll
    for (int kil = 0; kil < 4; ++kil) {
      s16x8 bfr[2];
#pragma unroll
      for (int ni = 0; ni < 2; ++ni) {
        int row = wx + ni * 16 + l16;
        int cl = (kil * 4 + quad) ^ (row & 7);
        bfr[ni] = *(const s16x8*)&buf[row * 128 + cl * 8];
      }
#pragma unroll
      for (int mi = 0; mi < 2; ++mi)
#pragma unroll
        for (int ni = 0; ni < 2; ++ni)
          acc[mi][ni] = __builtin_amdgcn_mfma_f32_16x16x32_bf16(
              afr[mi][kbase + kil], bfr[ni], acc[mi][ni], 0, 0, 0);
    }

    if (hs & 1) {  // d complete: fold into outacc, reset acc
      int d = hs >> 1;
#pragma unroll
      for (int mi = 0; mi < 2; ++mi) {
        int nl = (wy + mi * 16 + quad * 4) >> 3;
        float s = ewS[nl][d];
#pragma unroll
        for (int ni = 0; ni < 2; ++ni) {
#pragma unroll
          for (int r = 0; r < 4; ++r)
            outacc[mi][ni][r] += s * acc[mi][ni][r];
          acc[mi][ni] = (f32x4){0.f, 0.f, 0.f, 0.f};
        }
      }
    }

    asm volatile("s_waitcnt lgkmcnt(0)" ::: "memory");  // buf reads retired
    __builtin_amdgcn_s_barrier();
    if (hs + 2 < 32) STAGE_H(hs + 2);
  }
#undef STAGE_H

  // epilogue: bias + activation + store, straight from registers
#pragma unroll
  for (int mi = 0; mi < 2; ++mi)
#pragma unroll
    for (int ni = 0; ni < 2; ++ni)
#pragma unroll
      for (int r = 0; r < 4; ++r) {
        int row = row0 + wy + mi * 16 + quad * 4 + r;
        int n = row >> 3, b = row & 7;
        int o = ocbase + wx + ni * 16 + l16;
        float pre = outacc[mi][ni][r] + A.Bias[(size_t)mode * 1000 * O + n * O + o];
        if (is_gate) {
          float sg = 1.f / (1.f + __expf(-pre));
          if (o < 64) {
            float st = A.state[mode][(b * 1000 + n) * 64 + o];
            float zs = sg * st;
            A.ZSt[(size_t)mode * 524288 + (size_t)(b * 64 + o) * 1024 + n] = (u16)f2bf(zs);
            A.AgU[(size_t)mode * 2048000 + (size_t)row * 256 + 16 + o] = (u16)f2bf(zs);
          } else {
            A.Rb[(size_t)mode * 512000 + row * 64 + (o - 64)] = sg;
          }
        } else {
          float hc = tanhf(pre);
          float rr = A.Rb[(size_t)mode * 512000 + row * 64 + o];
          float st = A.state[mode][(b * 1000 + n) * 64 + o];
          A.out[(size_t)mode * 512000 + (b * 1000 + n) * 64 + o] = rr * st + (1.f - rr) * hc;
        }
      }
}

// ---------------------------------------------------------------------------
extern "C" void kernel_launch(void* const* d_in, const int* in_sizes, int n_in,
                              void* d_out, int out_size, void* d_ws, size_t ws_size,
                              hipStream_t stream) {
  const float* x[3]   = {(const float*)d_in[0], (const float*)d_in[1], (const float*)d_in[2]};
  const float* st[3]  = {(const float*)d_in[3], (const float*)d_in[4], (const float*)d_in[5]};
  const float* S[3]   = {(const float*)d_in[6], (const float*)d_in[7], (const float*)d_in[8]};
  const float* emb[3] = {(const float*)d_in[9], (const float*)d_in[10], (const float*)d_in[11]};
  const float* me = (const float*)d_in[12];
  const float* Wg = (const float*)d_in[13];
  const float* Bg = (const float*)d_in[14];
  const float* Wu = (const float*)d_in[15];
  const float* Bu = (const float*)d_in[16];
  float* out = (float*)d_out;

  float* BiG = (float*)d_ws;            // 3*1000*128
  float* BiU = BiG + 384000;            // 3*1000*64
  float* Rb  = BiU + 192000;            // 3*8000*64
  u16* S16 = (u16*)(Rb + 1536000);      // 3*1024*1024
  u16* Xt  = S16 + 3145728;             // 3*640*1024
  u16* T1t = Xt + 1966080;              // 3*640*1024
  u16* ZSt = T1t + 1966080;             // 3*512*1024
  u16* SZ1t= ZSt + 1572864;             // 3*512*1024
  u16* Ag  = SZ1t + 1572864;            // 3*8000*256
  u16* AgU = Ag + 6144000;              // 3*8000*256
  u16* BtG = AgU + 6144000;             // 2048*256
  u16* BtU = BtG + 524288;              // 1024*256

  {
    PrepArgs P;
    for (int m = 0; m < 3; ++m) { P.x[m] = x[m]; P.st[m] = st[m]; P.S[m] = S[m]; }
    P.S16 = S16; P.Xt = Xt; P.Ag = Ag; P.AgU = AgU; P.T1t = T1t; P.ZSt = ZSt; P.SZ1t = SZ1t;
    prep<<<32436, 256, 0, stream>>>(P);
  }
  bias_kernel<<<1500, 256, 0, stream>>>(emb[0], emb[1], emb[2], me, Bg, 128, BiG);
  bias_kernel<<<750, 256, 0, stream>>>(emb[0], emb[1], emb[2], me, Bu, 64, BiU);
  packW_kernel<<<3072, 256, 0, stream>>>(Wg, Wu, BtG, BtU);

  // cheb1: T1t = Xt @ S^T -> T1t + Ag[80..159] (+AgU x-part)
  {
    ChebArgs2 a;
    for (int m = 0; m < 3; ++m) {
      a.S16[m] = S16 + (size_t)m * 1048576; a.A[m] = Xt + (size_t)m * 655360;
      a.Res[m] = nullptr; a.Yt[m] = T1t + (size_t)m * 655360;
      a.AgA[m] = Ag + (size_t)m * 2048000; a.AgX[m] = AgU + (size_t)m * 2048000;
    }
    cheb_v4<<<dim3(16, 10, 3), 256, 0, stream>>>(a, 80, 80, 1.f, 0.f, 2 | 4);
  }
  // cheb2: T2t = 2*T1t @ S^T - Xt -> Ag[160..239] (+AgU x-part)
  {
    ChebArgs2 a;
    for (int m = 0; m < 3; ++m) {
      a.S16[m] = S16 + (size_t)m * 1048576; a.A[m] = T1t + (size_t)m * 655360;
      a.Res[m] = Xt + (size_t)m * 655360; a.Yt[m] = nullptr;
      a.AgA[m] = Ag + (size_t)m * 2048000; a.AgX[m] = AgU + (size_t)m * 2048000;
    }
    cheb_v4<<<dim3(16, 10, 3), 256, 0, stream>>>(a, 80, 160, 2.f, -1.f, 1 | 4);
  }
  // gate meta: reads Ag; writes ZSt + AgU[16..79] + Rb  (oc split: grid.x=2)
  {
    Meta3Args a;
    a.Ag = Ag; a.Bt = BtG; a.me = me; a.Bias = BiG;
    a.ZSt = ZSt; a.AgU = AgU; a.Rb = Rb; a.out = out;
    for (int m = 0; m < 3; ++m) { a.emb[m] = emb[m]; a.state[m] = st[m]; }
    meta3<<<dim3(2, 125, 3), 256, 0, stream>>>(a, 1, 128);
  }
  // cheb3: SZ1t = ZSt @ S^T -> SZ1t + AgU[96..159]
  {
    ChebArgs2 a;
    for (int m = 0; m < 3; ++m) {
      a.S16[m] = S16 + (size_t)m * 1048576; a.A[m] = ZSt + (size_t)m * 524288;
      a.Res[m] = nullptr; a.Yt[m] = SZ1t + (size_t)m * 524288;
      a.AgA[m] = AgU + (size_t)m * 2048000; a.AgX[m] = nullptr;
    }
    cheb_v4<<<dim3(16, 8, 3), 256, 0, stream>>>(a, 64, 96, 1.f, 0.f, 2);
  }
  // cheb4: SZ2t = 2*SZ1t @ S^T - ZSt -> AgU[176..239]
  {
    ChebArgs2 a;
    for (int m = 0; m < 3; ++m) {
      a.S16[m] = S16 + (size_t)m * 1048576; a.A[m] = SZ1t + (size_t)m * 524288;
      a.Res[m] = ZSt + (size_t)m * 524288; a.Yt[m] = nullptr;
      a.AgA[m] = AgU + (size_t)m * 2048000; a.AgX[m] = nullptr;
    }
    cheb_v4<<<dim3(16, 8, 3), 256, 0, stream>>>(a, 64, 176, 2.f, -1.f, 1);
  }
  // update meta: reads AgU; writes out
  {
    Meta3Args a;
    a.Ag = AgU; a.Bt = BtU; a.me = me; a.Bias = BiU;
    a.ZSt = ZSt; a.AgU = AgU; a.Rb = Rb; a.out = out;
    for (int m = 0; m < 3; ++m) { a.emb[m] = emb[m]; a.state[m] = st[m]; }
    meta3<<<dim3(1, 125, 3), 256, 0, stream>>>(a, 0, 64);
  }
}

// Round 7
// 262.299 us; speedup vs baseline: 2.2089x; 1.5611x over previous
//
#include <hip/hip_runtime.h>
#include <math.h>

// ---------------------------------------------------------------------------
// HimNet multimode v11. B=8,N=1000,CIN=16,H=64,D=16,K=3,XIN=80,K*XIN=240,2H=128
//
// v11 = v6 meta3 (proven best: 52.5us, 4 blocks/CU, single-buffer
// __syncthreads loop) + vectorized prep (4 elems/thread, float4 reads,
// u64 stores) + bias/packW merged into one aux launch.
// Lessons encoded: (v5,v10) counted-vmcnt pipelines break L2 locality or
// occupancy here; (v8,v9) afr must stay AGPR-resident - never force "v".
// ---------------------------------------------------------------------------

typedef __attribute__((ext_vector_type(8))) short s16x8;
typedef __attribute__((ext_vector_type(4))) float f32x4;
typedef unsigned short u16;
typedef unsigned int u32;
typedef unsigned long long u64;

__device__ __forceinline__ u32 f2bf(float f) {
  union { float f; u32 u; } v; v.f = f;
  return (v.u + 0x7FFFu + ((v.u >> 16) & 1u)) >> 16;  // RNE
}
__device__ __forceinline__ float bf2f(u16 h) {
  union { u32 u; float f; } v; v.u = (u32)h << 16; return v.f;
}
__device__ __forceinline__ u64 pk4(float a, float b, float c, float d) {
  return (u64)f2bf(a) | ((u64)f2bf(b) << 16) | ((u64)f2bf(c) << 32) |
         ((u64)f2bf(d) << 48);
}
__device__ __forceinline__ void glds16(const u16* g, u16* l) {
  __builtin_amdgcn_global_load_lds(
      (const __attribute__((address_space(1))) void*)g,
      (__attribute__((address_space(3))) void*)l, 16, 0, 0);
}

// ---------------------------------------------------------------------------
// prep_v: vectorized 4 elems/thread. Regions (element counts, all %4==0):
// S16[3][1024][1024], Xt[3][640][1024], Ag kc0, Ag K-pad, AgU x, AgU K-pad,
// n-pad rows of T1t/ZSt/SZ1t.
// ---------------------------------------------------------------------------
#define E0 3145728
#define E1 1966080
#define E2 1920000
#define E3 384000
#define E4 384000
#define E5 384000
#define E6 119808
// total = 8303616 elems = 2075904 threads = 8109 * 256

struct PrepArgs {
  const float* x[3]; const float* st[3]; const float* S[3];
  u16 *S16, *Xt, *Ag, *AgU, *T1t, *ZSt, *SZ1t;
};

__global__ void prep_v(PrepArgs P) {
  long idx = ((long)blockIdx.x * 256 + threadIdx.x) * 4;
  if (idx < E0) {  // S16 incl pads: 4 consecutive k, same n
    int m = (int)(idx >> 20); int rem = (int)(idx & 1048575);
    int n = rem >> 10, k = rem & 1023;
    u64 pv = 0;
    if (n < 1000 && k < 1000) {
      f32x4 v = *(const f32x4*)&P.S[m][n * 1000 + k];
      pv = pk4(v[0], v[1], v[2], v[3]);
    }
    *(u64*)&P.S16[(size_t)m * 1048576 + rem] = pv; return;
  }
  idx -= E0;
  if (idx < E1) {  // Xt: 4 consecutive nn, same col
    int m = (int)(idx / 655360); int rem = (int)(idx % 655360);
    int col = rem >> 10, nn = rem & 1023;
    int b = col / 80, c = col % 80;
    u64 pv = 0;
    if (nn < 1000) {
      float f[4];
#pragma unroll
      for (int j = 0; j < 4; ++j)
        f[j] = (c < 16) ? P.x[m][(b * 1000 + nn + j) * 16 + c]
                        : P.st[m][(b * 1000 + nn + j) * 64 + c - 16];
      pv = pk4(f[0], f[1], f[2], f[3]);
    }
    *(u64*)&P.Xt[(size_t)m * 655360 + rem] = pv; return;
  }
  idx -= E1;
  if (idx < E2) {  // Ag kc0: 4 consecutive c, same r (boundary 16 is %4==0)
    int m = (int)(idx / 640000); int rem = (int)(idx % 640000);
    int r = rem / 80, c = rem % 80;
    int n = r >> 3, b = r & 7;
    f32x4 v = (c < 16) ? *(const f32x4*)&P.x[m][(b * 1000 + n) * 16 + c]
                       : *(const f32x4*)&P.st[m][(b * 1000 + n) * 64 + c - 16];
    *(u64*)&P.Ag[(size_t)m * 2048000 + (size_t)r * 256 + c] =
        pk4(v[0], v[1], v[2], v[3]);
    return;
  }
  idx -= E2;
  if (idx < E3) {  // Ag K-pad 240..255
    int m = (int)(idx / 128000); int rem = (int)(idx % 128000);
    int r = rem / 16, c = 240 + rem % 16;
    *(u64*)&P.Ag[(size_t)m * 2048000 + (size_t)r * 256 + c] = 0; return;
  }
  idx -= E3;
  if (idx < E4) {  // AgU kc0 x-part (cols 0..15)
    int m = (int)(idx / 128000); int rem = (int)(idx % 128000);
    int r = rem / 16, c = rem % 16;
    int n = r >> 3, b = r & 7;
    f32x4 v = *(const f32x4*)&P.x[m][(b * 1000 + n) * 16 + c];
    *(u64*)&P.AgU[(size_t)m * 2048000 + (size_t)r * 256 + c] =
        pk4(v[0], v[1], v[2], v[3]);
    return;
  }
  idx -= E4;
  if (idx < E5) {  // AgU K-pad
    int m = (int)(idx / 128000); int rem = (int)(idx % 128000);
    int r = rem / 16, c = 240 + rem % 16;
    *(u64*)&P.AgU[(size_t)m * 2048000 + (size_t)r * 256 + c] = 0; return;
  }
  idx -= E5;
  if (idx < E6) {  // n-pad rows (k=1000..1023) of T1t/ZSt/SZ1t
    int m = (int)(idx / 39936); int rem = (int)(idx % 39936);
    if (rem < 15360) { int col = rem / 24, j = rem % 24;
      *(u64*)&P.T1t[(size_t)m * 655360 + col * 1024 + 1000 + j] = 0; }
    else if (rem < 27648) { int e = rem - 15360; int col = e / 24, j = e % 24;
      *(u64*)&P.ZSt[(size_t)m * 524288 + col * 1024 + 1000 + j] = 0; }
    else { int e = rem - 27648; int col = e / 24, j = e % 24;
      *(u64*)&P.SZ1t[(size_t)m * 524288 + col * 1024 + 1000 + j] = 0; }
    return;
  }
}

// ---------------------------------------------------------------------------
// aux: BiG (384000) + BiU (192000) + packW gate (524288) + packW upd (262144)
// in one launch. total = 1362432 = 5322 * 256.
// ---------------------------------------------------------------------------
__global__ void aux_kernel(const float* __restrict__ e0, const float* __restrict__ e1,
                           const float* __restrict__ e2, const float* __restrict__ me,
                           const float* __restrict__ Bg, const float* __restrict__ Bu,
                           const float* __restrict__ Wg, const float* __restrict__ Wu,
                           float* __restrict__ BiG, float* __restrict__ BiU,
                           u16* __restrict__ BtG, u16* __restrict__ BtU) {
  int idx = blockIdx.x * blockDim.x + threadIdx.x;
  if (idx < 384000) {        // BiG[mode][n*128+o]
    int mode = idx / 128000, rem = idx % 128000;
    int n = rem >> 7, o = rem & 127;
    const float* emb = (mode == 0) ? e0 : (mode == 1) ? e1 : e2;
    float s = 0.f;
#pragma unroll
    for (int d = 0; d < 16; ++d)
      s += emb[n * 16 + d] * me[mode * 16 + d] * Bg[d * 128 + o];
    BiG[idx] = s; return;
  }
  idx -= 384000;
  if (idx < 192000) {        // BiU[mode][n*64+o]
    int mode = idx / 64000, rem = idx % 64000;
    int n = rem >> 6, o = rem & 63;
    const float* emb = (mode == 0) ? e0 : (mode == 1) ? e1 : e2;
    float s = 0.f;
#pragma unroll
    for (int d = 0; d < 16; ++d)
      s += emb[n * 16 + d] * me[mode * 16 + d] * Bu[d * 64 + o];
    BiU[idx] = s; return;
  }
  idx -= 192000;
  if (idx < 524288) {        // BtG d-major: [(d*128+o)][k]
    int col = idx >> 8, k = idx & 255;
    int d = col >> 7, o = col & 127;
    BtG[idx] = (k < 240) ? (u16)f2bf(Wg[d * 30720 + k * 128 + o]) : (u16)0;
    return;
  }
  idx -= 524288;
  {                          // BtU d-major: [(d*64+o)][k]
    int col = idx >> 8, k = idx & 255;
    int d = col >> 6, o = col & 63;
    BtU[idx] = (k < 240) ? (u16)f2bf(Wu[d * 15360 + k * 64 + o]) : (u16)0;
  }
}

// ---------------------------------------------------------------------------
// cheb_v4: D[f][n] = alpha*sum_k A[f][k]*S16[n][k] (+beta*Res[f][n])
// Tile 64(f) x 64(n), BK=64, 256 thr = 4 waves in 2x2 grid (32x32 each).
// glds staging, XOR chunk swizzle c^(row&7). flags: 1=hasRes,2=hasY,4=hasAgX
// ---------------------------------------------------------------------------
struct ChebArgs2 {
  const u16* S16[3]; const u16* A[3]; const u16* Res[3];
  u16* Yt[3]; u16* AgA[3]; u16* AgX[3];
};

__global__ __launch_bounds__(256, 2) void cheb_v4(ChebArgs2 g, int fdiv, int agbase,
                                                  float alpha, float beta, int flags) {
  const int mode = blockIdx.z;
  const u16* __restrict__ Ab = g.A[mode];
  const u16* __restrict__ Sb = g.S16[mode];

  __shared__ u16 As[64 * 64];
  __shared__ u16 Bs[64 * 64];

  const int t = threadIdx.x;
  const int row0 = blockIdx.y * 64, n0 = blockIdx.x * 64;
  const int lane = t & 63, wid = t >> 6;
  const int l16 = lane & 15, quad = lane >> 4;
  const int wy = (wid >> 1) * 32, wx = (wid & 1) * 32;

  f32x4 acc[2][2];
#pragma unroll
  for (int a = 0; a < 2; ++a)
#pragma unroll
    for (int b = 0; b < 2; ++b) acc[a][b] = (f32x4){0.f, 0.f, 0.f, 0.f};

  for (int k0 = 0; k0 < 1024; k0 += 64) {
#pragma unroll
    for (int p = 0; p < 2; ++p) {  // A: 64x64 = 512 chunks
      int idx = p * 256 + t; int row = idx >> 3; int cs = (idx & 7) ^ (row & 7);
      glds16(Ab + (size_t)(row0 + row) * 1024 + k0 + cs * 8, &As[idx * 8]);
    }
#pragma unroll
    for (int p = 0; p < 2; ++p) {  // B: 64x64 = 512 chunks
      int idx = p * 256 + t; int row = idx >> 3; int cs = (idx & 7) ^ (row & 7);
      glds16(Sb + (size_t)(n0 + row) * 1024 + k0 + cs * 8, &Bs[idx * 8]);
    }
    __syncthreads();
    s16x8 af[2][2], bf[2][2];
#pragma unroll
    for (int mi = 0; mi < 2; ++mi) {
      int row = wy + mi * 16 + l16;
#pragma unroll
      for (int ks = 0; ks < 2; ++ks) {
        int cl = (ks * 4 + quad) ^ (row & 7);
        af[mi][ks] = *(const s16x8*)&As[row * 64 + cl * 8];
      }
    }
#pragma unroll
    for (int ni = 0; ni < 2; ++ni) {
      int row = wx + ni * 16 + l16;
#pragma unroll
      for (int ks = 0; ks < 2; ++ks) {
        int cl = (ks * 4 + quad) ^ (row & 7);
        bf[ni][ks] = *(const s16x8*)&Bs[row * 64 + cl * 8];
      }
    }
#pragma unroll
    for (int ks = 0; ks < 2; ++ks)
#pragma unroll
      for (int mi = 0; mi < 2; ++mi)
#pragma unroll
        for (int ni = 0; ni < 2; ++ni)
          acc[mi][ni] = __builtin_amdgcn_mfma_f32_16x16x32_bf16(af[mi][ks], bf[ni][ks], acc[mi][ni], 0, 0, 0);
    __syncthreads();
  }

#pragma unroll
  for (int mi = 0; mi < 2; ++mi) {
    int frow0 = row0 + wy + mi * 16 + quad * 4;
    int b = frow0 / fdiv, c0 = frow0 - b * fdiv;
#pragma unroll
    for (int ni = 0; ni < 2; ++ni) {
      int n = n0 + wx + ni * 16 + l16;
      if (n < 1000) {
        u16 pk[4];
#pragma unroll
        for (int r = 0; r < 4; ++r) {
          float v = alpha * acc[mi][ni][r];
          if (flags & 1) v += beta * bf2f(g.Res[mode][(size_t)(frow0 + r) * 1024 + n]);
          u16 h = (u16)f2bf(v);
          pk[r] = h;
          if (flags & 2) g.Yt[mode][(size_t)(frow0 + r) * 1024 + n] = h;
        }
        u64 pv = (u64)pk[0] | ((u64)pk[1] << 16) | ((u64)pk[2] << 32) | ((u64)pk[3] << 48);
        *(u64*)&g.AgA[mode][(size_t)(n * 8 + b) * 256 + agbase + c0] = pv;
        if ((flags & 4) && c0 < 16)
          *(u64*)&g.AgX[mode][(size_t)(n * 8 + b) * 256 + agbase + c0] = pv;
      }
    }
  }
}

// ---------------------------------------------------------------------------
// meta3 (v6, proven): out[r,o] = act( sum_d ew[n,d]*(A[r,:].Btd[d*O+o,:]) + b )
// Block: 64 rows x 64 out-cols (oc = blockIdx.x). Prologue stages A THROUGH
// Bs, hoists fragments to registers (AGPR-resident); then 16 d-tiles of B
// single-buffered in Bs with __syncthreads. LDS 33.3KB -> 4 blocks/CU.
// ---------------------------------------------------------------------------
struct Meta3Args {
  const u16* Ag;        // [3][8000][256]
  const u16* Bt;        // [O*16][256] d-major
  const float* emb[3];
  const float* me;
  const float* Bias;    // [3][1000][O]
  const float* state[3];
  u16* ZSt;             // [3][512][1024]
  u16* AgU;             // [3][8000][256]
  float* Rb;            // [3][8000][64]
  float* out;
};

__global__ __launch_bounds__(256, 4) void meta3(Meta3Args A, int is_gate, int O) {
  const int mode = blockIdx.z;
  const int row0 = blockIdx.y * 64;
  const int n0 = row0 >> 3;
  const int oc = blockIdx.x;          // out-col block: gate 0/1, update 0
  const int ocbase = oc * 64;

  __shared__ u16 Bs[64 * 256];   // 32KB: A-stage in prologue, then B tiles
  __shared__ float ewS[8][17];

  const int t = threadIdx.x;
  if (t < 128) {
    int nl = t >> 4, d = t & 15;
    ewS[nl][d] = A.emb[mode][(n0 + nl) * 16 + d] * A.me[mode * 16 + d];
  }

  const int lane = t & 63, wid = t >> 6;
  const int l16 = lane & 15, quad = lane >> 4;
  const int wy = (wid >> 1) * 32, wx = (wid & 1) * 32;
  const u16* Agm = A.Ag + (size_t)mode * 2048000;

  // prologue: stage A rows [row0,row0+64) x K256 into Bs, hoist to registers
#pragma unroll
  for (int p = 0; p < 8; ++p) {
    int idx = p * 256 + t; int row = idx >> 5; int cs = (idx & 31) ^ (row & 7);
    glds16(Agm + (size_t)(row0 + row) * 256 + cs * 8, &Bs[idx * 8]);
  }
  __syncthreads();

  s16x8 afr[2][8];   // AGPR-resident (unified file); no class constraints
#pragma unroll
  for (int mi = 0; mi < 2; ++mi) {
    int row = wy + mi * 16 + l16;
#pragma unroll
    for (int ki = 0; ki < 8; ++ki) {
      int cl = (ki * 4 + quad) ^ (row & 7);
      afr[mi][ki] = *(const s16x8*)&Bs[row * 256 + cl * 8];
    }
  }
  __syncthreads();   // hoist reads retired before Bs is overwritten

  f32x4 outacc[2][2];
#pragma unroll
  for (int a = 0; a < 2; ++a)
#pragma unroll
    for (int b = 0; b < 2; ++b) outacc[a][b] = (f32x4){0.f, 0.f, 0.f, 0.f};

  for (int tl = 0; tl < 16; ++tl) {           // tl == d
    const int brow0 = tl * O + ocbase;
#pragma unroll
    for (int p = 0; p < 8; ++p) {
      int idx = p * 256 + t; int row = idx >> 5; int cs = (idx & 31) ^ (row & 7);
      glds16(A.Bt + (size_t)(brow0 + row) * 256 + cs * 8, &Bs[idx * 8]);
    }
    __syncthreads();   // B tile staged

    f32x4 acc[2][2];
#pragma unroll
    for (int a = 0; a < 2; ++a)
#pragma unroll
      for (int b = 0; b < 2; ++b) acc[a][b] = (f32x4){0.f, 0.f, 0.f, 0.f};

#pragma unroll
    for (int ki = 0; ki < 8; ++ki) {
      s16x8 bfr[2];
#pragma unroll
      for (int ni = 0; ni < 2; ++ni) {
        int row = wx + ni * 16 + l16;
        int cl = (ki * 4 + quad) ^ (row & 7);
        bfr[ni] = *(const s16x8*)&Bs[row * 256 + cl * 8];
      }
#pragma unroll
      for (int mi = 0; mi < 2; ++mi)
#pragma unroll
        for (int ni = 0; ni < 2; ++ni)
          acc[mi][ni] = __builtin_amdgcn_mfma_f32_16x16x32_bf16(afr[mi][ki], bfr[ni], acc[mi][ni], 0, 0, 0);
    }

    // fold d: outacc += ew[n,d] * acc
#pragma unroll
    for (int mi = 0; mi < 2; ++mi) {
      int nl = (wy + mi * 16 + quad * 4) >> 3;
      float s = ewS[nl][tl];
#pragma unroll
      for (int ni = 0; ni < 2; ++ni)
#pragma unroll
        for (int r = 0; r < 4; ++r)
          outacc[mi][ni][r] += s * acc[mi][ni][r];
    }
    __syncthreads();   // Bs reads retired before next tile's stage
  }

  // epilogue: bias + activation + store, straight from registers
#pragma unroll
  for (int mi = 0; mi < 2; ++mi)
#pragma unroll
    for (int ni = 0; ni < 2; ++ni)
#pragma unroll
      for (int r = 0; r < 4; ++r) {
        int row = row0 + wy + mi * 16 + quad * 4 + r;
        int n = row >> 3, b = row & 7;
        int o = ocbase + wx + ni * 16 + l16;
        float pre = outacc[mi][ni][r] + A.Bias[(size_t)mode * 1000 * O + n * O + o];
        if (is_gate) {
          float sg = 1.f / (1.f + __expf(-pre));
          if (o < 64) {
            float st = A.state[mode][(b * 1000 + n) * 64 + o];
            float zs = sg * st;
            A.ZSt[(size_t)mode * 524288 + (size_t)(b * 64 + o) * 1024 + n] = (u16)f2bf(zs);
            A.AgU[(size_t)mode * 2048000 + (size_t)row * 256 + 16 + o] = (u16)f2bf(zs);
          } else {
            A.Rb[(size_t)mode * 512000 + row * 64 + (o - 64)] = sg;
          }
        } else {
          float hc = tanhf(pre);
          float rr = A.Rb[(size_t)mode * 512000 + row * 64 + o];
          float st = A.state[mode][(b * 1000 + n) * 64 + o];
          A.out[(size_t)mode * 512000 + (b * 1000 + n) * 64 + o] = rr * st + (1.f - rr) * hc;
        }
      }
}

// ---------------------------------------------------------------------------
extern "C" void kernel_launch(void* const* d_in, const int* in_sizes, int n_in,
                              void* d_out, int out_size, void* d_ws, size_t ws_size,
                              hipStream_t stream) {
  const float* x[3]   = {(const float*)d_in[0], (const float*)d_in[1], (const float*)d_in[2]};
  const float* st[3]  = {(const float*)d_in[3], (const float*)d_in[4], (const float*)d_in[5]};
  const float* S[3]   = {(const float*)d_in[6], (const float*)d_in[7], (const float*)d_in[8]};
  const float* emb[3] = {(const float*)d_in[9], (const float*)d_in[10], (const float*)d_in[11]};
  const float* me = (const float*)d_in[12];
  const float* Wg = (const float*)d_in[13];
  const float* Bg = (const float*)d_in[14];
  const float* Wu = (const float*)d_in[15];
  const float* Bu = (const float*)d_in[16];
  float* out = (float*)d_out;

  float* BiG = (float*)d_ws;            // 3*1000*128
  float* BiU = BiG + 384000;            // 3*1000*64
  float* Rb  = BiU + 192000;            // 3*8000*64
  u16* S16 = (u16*)(Rb + 1536000);      // 3*1024*1024
  u16* Xt  = S16 + 3145728;             // 3*640*1024
  u16* T1t = Xt + 1966080;              // 3*640*1024
  u16* ZSt = T1t + 1966080;             // 3*512*1024
  u16* SZ1t= ZSt + 1572864;             // 3*512*1024
  u16* Ag  = SZ1t + 1572864;            // 3*8000*256
  u16* AgU = Ag + 6144000;              // 3*8000*256
  u16* BtG = AgU + 6144000;             // 2048*256
  u16* BtU = BtG + 524288;              // 1024*256

  {
    PrepArgs P;
    for (int m = 0; m < 3; ++m) { P.x[m] = x[m]; P.st[m] = st[m]; P.S[m] = S[m]; }
    P.S16 = S16; P.Xt = Xt; P.Ag = Ag; P.AgU = AgU; P.T1t = T1t; P.ZSt = ZSt; P.SZ1t = SZ1t;
    prep_v<<<8109, 256, 0, stream>>>(P);
  }
  aux_kernel<<<5322, 256, 0, stream>>>(emb[0], emb[1], emb[2], me, Bg, Bu,
                                       Wg, Wu, BiG, BiU, BtG, BtU);

  // cheb1: T1t = Xt @ S^T -> T1t + Ag[80..159] (+AgU x-part)
  {
    ChebArgs2 a;
    for (int m = 0; m < 3; ++m) {
      a.S16[m] = S16 + (size_t)m * 1048576; a.A[m] = Xt + (size_t)m * 655360;
      a.Res[m] = nullptr; a.Yt[m] = T1t + (size_t)m * 655360;
      a.AgA[m] = Ag + (size_t)m * 2048000; a.AgX[m] = AgU + (size_t)m * 2048000;
    }
    cheb_v4<<<dim3(16, 10, 3), 256, 0, stream>>>(a, 80, 80, 1.f, 0.f, 2 | 4);
  }
  // cheb2: T2t = 2*T1t @ S^T - Xt -> Ag[160..239] (+AgU x-part)
  {
    ChebArgs2 a;
    for (int m = 0; m < 3; ++m) {
      a.S16[m] = S16 + (size_t)m * 1048576; a.A[m] = T1t + (size_t)m * 655360;
      a.Res[m] = Xt + (size_t)m * 655360; a.Yt[m] = nullptr;
      a.AgA[m] = Ag + (size_t)m * 2048000; a.AgX[m] = AgU + (size_t)m * 2048000;
    }
    cheb_v4<<<dim3(16, 10, 3), 256, 0, stream>>>(a, 80, 160, 2.f, -1.f, 1 | 4);
  }
  // gate meta: reads Ag; writes ZSt + AgU[16..79] + Rb  (oc split: grid.x=2)
  {
    Meta3Args a;
    a.Ag = Ag; a.Bt = BtG; a.me = me; a.Bias = BiG;
    a.ZSt = ZSt; a.AgU = AgU; a.Rb = Rb; a.out = out;
    for (int m = 0; m < 3; ++m) { a.emb[m] = emb[m]; a.state[m] = st[m]; }
    meta3<<<dim3(2, 125, 3), 256, 0, stream>>>(a, 1, 128);
  }
  // cheb3: SZ1t = ZSt @ S^T -> SZ1t + AgU[96..159]
  {
    ChebArgs2 a;
    for (int m = 0; m < 3; ++m) {
      a.S16[m] = S16 + (size_t)m * 1048576; a.A[m] = ZSt + (size_t)m * 524288;
      a.Res[m] = nullptr; a.Yt[m] = SZ1t + (size_t)m * 524288;
      a.AgA[m] = AgU + (size_t)m * 2048000; a.AgX[m] = nullptr;
    }
    cheb_v4<<<dim3(16, 8, 3), 256, 0, stream>>>(a, 64, 96, 1.f, 0.f, 2);
  }
  // cheb4: SZ2t = 2*SZ1t @ S^T - ZSt -> AgU[176..239]
  {
    ChebArgs2 a;
    for (int m = 0; m < 3; ++m) {
      a.S16[m] = S16 + (size_t)m * 1048576; a.A[m] = SZ1t + (size_t)m * 524288;
      a.Res[m] = ZSt + (size_t)m * 524288; a.Yt[m] = nullptr;
      a.AgA[m] = AgU + (size_t)m * 2048000; a.AgX[m] = nullptr;
    }
    cheb_v4<<<dim3(16, 8, 3), 256, 0, stream>>>(a, 64, 176, 2.f, -1.f, 1);
  }
  // update meta: reads AgU; writes out
  {
    Meta3Args a;
    a.Ag = AgU; a.Bt = BtU; a.me = me; a.Bias = BiU;
    a.ZSt = ZSt; a.AgU = AgU; a.Rb = Rb; a.out = out;
    for (int m = 0; m < 3; ++m) { a.emb[m] = emb[m]; a.state[m] = st[m]; }
    meta3<<<dim3(1, 125, 3), 256, 0, stream>>>(a, 0, 64);
  }
}